// Round 2
// baseline (1728.092 us; speedup 1.0000x reference)
//
#include <hip/hip_runtime.h>
#include <hip/hip_bf16.h>
#include <cstdint>
#include <cstddef>

typedef __attribute__((ext_vector_type(8))) short bf16x8;
typedef __attribute__((ext_vector_type(4))) float f32x4;
typedef unsigned short u16;

#define D_MODEL 1024
#define N_HEADS 16
#define SEQ 1024
#define BATCH 4
#define NLAYER 2
#define FFN_DIM 4096
#define VOCAB 32000
#define MROWS (BATCH*SEQ)

__device__ __forceinline__ u16 f2b(float f) {
  union { float f; unsigned u; } v; v.f = f;
  unsigned r = v.u + 0x7fffu + ((v.u >> 16) & 1u);
  return (u16)(r >> 16);
}

__device__ __forceinline__ void async16(const u16* g, u16* l) {
  __builtin_amdgcn_global_load_lds(
      (const __attribute__((address_space(1))) void*)g,
      (__attribute__((address_space(3))) void*)l, 16, 0, 0);
}

__device__ __forceinline__ f32x4 mfma_bf16(bf16x8 a, bf16x8 b, f32x4 c) {
  return __builtin_amdgcn_mfma_f32_16x16x32_bf16(a, b, c, 0, 0, 0);
}

// ---------------- f32 -> bf16 convert (grid-stride, vectorized) ----------------
__global__ __launch_bounds__(256) void cvt_f32_bf16(const float* __restrict__ in,
                                                    u16* __restrict__ out, int n4) {
  for (int i = blockIdx.x * 256 + threadIdx.x; i < n4; i += gridDim.x * 256) {
    float4 v = ((const float4*)in)[i];
    ushort4 o;
    o.x = f2b(v.x); o.y = f2b(v.y); o.z = f2b(v.z); o.w = f2b(v.w);
    ((ushort4*)out)[i] = o;
  }
}

// ---------------- embedding + positional encoding (fp32) ----------------
__global__ __launch_bounds__(256) void embed_kernel(const int* __restrict__ tokens,
                                                    const float* __restrict__ emb,
                                                    float* __restrict__ x) {
  int row = blockIdx.x;            // 0..4095  (= b*S + s)
  int s = row & (SEQ - 1);
  int tok = tokens[row];
  int t = threadIdx.x;
  int d0 = t * 4;
  const float C = 0.0089944730194708f;   // ln(10000)/1024
  float ang0 = (float)s * expf(-(float)d0 * C);
  float ang1 = (float)s * expf(-(float)(d0 + 2) * C);
  float4 e = ((const float4*)(emb + (size_t)tok * D_MODEL))[t];
  float4 r;
  r.x = e.x * 32.0f + sinf(ang0);
  r.y = e.y * 32.0f + cosf(ang0);
  r.z = e.z * 32.0f + sinf(ang1);
  r.w = e.w * 32.0f + cosf(ang1);
  ((float4*)(x + (size_t)row * D_MODEL))[t] = r;
}

// ---------------- layernorm (torch-style: unbiased std, /(std+eps)) ----------------
__global__ __launch_bounds__(256) void ln_kernel(const float* __restrict__ x,
                                                 const float* __restrict__ ga,
                                                 const float* __restrict__ be,
                                                 u16* __restrict__ y) {
  int row = blockIdx.x;
  int t = threadIdx.x;
  const float* xr = x + (size_t)row * D_MODEL;
  float4 v = ((const float4*)xr)[t];
  float sum = v.x + v.y + v.z + v.w;
  float sq = v.x * v.x + v.y * v.y + v.z * v.z + v.w * v.w;
#pragma unroll
  for (int m = 1; m < 64; m <<= 1) { sum += __shfl_xor(sum, m); sq += __shfl_xor(sq, m); }
  __shared__ float rs[4], rq[4];
  int wid = t >> 6, lane = t & 63;
  if (lane == 0) { rs[wid] = sum; rq[wid] = sq; }
  __syncthreads();
  sum = rs[0] + rs[1] + rs[2] + rs[3];
  sq = rq[0] + rq[1] + rq[2] + rq[3];
  float mean = sum * (1.0f / D_MODEL);
  float var = fmaxf((sq - sum * mean) * (1.0f / (D_MODEL - 1)), 0.0f);
  float inv = 1.0f / (sqrtf(var) + 1e-6f);
  float4 g = ((const float4*)ga)[t];
  float4 bb = ((const float4*)be)[t];
  ushort4 o;
  o.x = f2b(g.x * (v.x - mean) * inv + bb.x);
  o.y = f2b(g.y * (v.y - mean) * inv + bb.y);
  o.z = f2b(g.z * (v.z - mean) * inv + bb.z);
  o.w = f2b(g.w * (v.w - mean) * inv + bb.w);
  ((ushort4*)(y + (size_t)row * D_MODEL))[t] = o;
}

// ---------------- bf16 MFMA GEMM:  C[M,N] = A[M,K] * W[N,K]^T + bias ----------------
// MODE 0: store bf16.  1: relu, store bf16.  2: Cf[idx] += v (fp32 residual RMW).
// MODE 3: store fp32.
template <int MODE>
__global__ __launch_bounds__(256) void gemm_bt(const u16* __restrict__ A,
                                               const u16* __restrict__ W,
                                               const float* __restrict__ bias,
                                               u16* __restrict__ Cb,
                                               float* __restrict__ Cf,
                                               int N, int K) {
  __shared__ u16 As[2][128 * 32];
  __shared__ u16 Bs[2][128 * 32];
  const int tid = threadIdx.x;
  const int bn0 = blockIdx.x * 128, bm0 = blockIdx.y * 128;
  const int lane = tid & 63, wid = tid >> 6;
  const int lr = lane & 15, lk = lane >> 4;
  const int wr = wid >> 1, wc = wid & 1;
  const u16* Ag = A + (size_t)(bm0 + (tid >> 2)) * K + (tid & 3) * 8;
  const u16* Wg = W + (size_t)(bn0 + (tid >> 2)) * K + (tid & 3) * 8;
  const int ldst = tid * 8;
  auto stage = [&](int kt, int b) {
    const u16* a0 = Ag + kt * 32;
    const u16* w0 = Wg + kt * 32;
    async16(a0, &As[b][ldst]);
    async16(a0 + (size_t)64 * K, &As[b][2048 + ldst]);
    async16(w0, &Bs[b][ldst]);
    async16(w0 + (size_t)64 * K, &Bs[b][2048 + ldst]);
  };
  f32x4 acc[4][4] = {};
  const int nk = K >> 5;
  stage(0, 0);
  for (int kt = 0; kt < nk; ++kt) {
    __syncthreads();                       // staged tile kt visible (vmcnt drained)
    if (kt + 1 < nk) stage(kt + 1, (kt + 1) & 1);
    const u16* Ab = As[kt & 1];
    const u16* Bb = Bs[kt & 1];
    bf16x8 af[4], bfr[4];
#pragma unroll
    for (int mi = 0; mi < 4; mi++)
      af[mi] = *(const bf16x8*)&Ab[(wr * 64 + mi * 16 + lr) * 32 + lk * 8];
#pragma unroll
    for (int ni = 0; ni < 4; ni++)
      bfr[ni] = *(const bf16x8*)&Bb[(wc * 64 + ni * 16 + lr) * 32 + lk * 8];
#pragma unroll
    for (int mi = 0; mi < 4; mi++)
#pragma unroll
      for (int ni = 0; ni < 4; ni++)
        acc[mi][ni] = mfma_bf16(af[mi], bfr[ni], acc[mi][ni]);
  }
#pragma unroll
  for (int mi = 0; mi < 4; mi++) {
    const int r0 = bm0 + wr * 64 + mi * 16 + lk * 4;
#pragma unroll
    for (int ni = 0; ni < 4; ni++) {
      const int col = bn0 + wc * 64 + ni * 16 + lr;
      const float bv = bias[col];
#pragma unroll
      for (int j = 0; j < 4; j++) {
        float v = acc[mi][ni][j] + bv;
        size_t idx = (size_t)(r0 + j) * N + col;
        if (MODE == 0) Cb[idx] = f2b(v);
        else if (MODE == 1) Cb[idx] = f2b(fmaxf(v, 0.0f));
        else if (MODE == 2) Cf[idx] += v;
        else Cf[idx] = v;
      }
    }
  }
}

// ---------------- flash attention: block = (qt, h, b), 64 q-rows, KBLK=64 ----------------
__global__ __launch_bounds__(256) void attn_kernel(const u16* __restrict__ qkv,
                                                   u16* __restrict__ o) {
  const int qt = blockIdx.x, h = blockIdx.y, bb = blockIdx.z;
  const int tid = threadIdx.x, wid = tid >> 6, lane = tid & 63;
  const int lr = lane & 15, lk = lane >> 4;
  __shared__ u16 Qs[64 * 64], Ks[64 * 64], Vs[64 * 64], Ps[64 * 64];
  const size_t base = (size_t)bb * SEQ * 3072;
  {
    const u16* q0 = qkv + base + (size_t)(qt * 64 + (tid >> 3)) * 3072 + h * 64 + (tid & 7) * 8;
    async16(q0, &Qs[tid * 8]);
    async16(q0 + (size_t)32 * 3072, &Qs[2048 + tid * 8]);
  }
  float mrow[4] = {-1e30f, -1e30f, -1e30f, -1e30f};
  float lrow[4] = {0.f, 0.f, 0.f, 0.f};
  f32x4 accO[4] = {};
  const int vr = tid >> 2, vc0 = (tid & 3) * 16;
  for (int kt = 0; kt < SEQ / 64; ++kt) {
    // stage K (async direct-to-LDS) and V (reg-staged transpose)
    const u16* k0 = qkv + base + (size_t)(kt * 64 + (tid >> 3)) * 3072 + 1024 + h * 64 + (tid & 7) * 8;
    async16(k0, &Ks[tid * 8]);
    async16(k0 + (size_t)32 * 3072, &Ks[2048 + tid * 8]);
    const u16* v0 = qkv + base + (size_t)(kt * 64 + vr) * 3072 + 2048 + h * 64 + vc0;
    bf16x8 va = *(const bf16x8*)v0;
    bf16x8 vb = *(const bf16x8*)(v0 + 8);
#pragma unroll
    for (int i = 0; i < 8; i++) {
      Vs[(vc0 + i) * 64 + vr] = (u16)va[i];
      Vs[(vc0 + 8 + i) * 64 + vr] = (u16)vb[i];
    }
    __syncthreads();   // Q(first iter)+K staged, V^T visible
    // QK^T : wave wid owns q-rows wid*16..+16, all 64 k-cols
    f32x4 s[4] = {};
#pragma unroll
    for (int ks = 0; ks < 2; ks++) {
      bf16x8 aq = *(const bf16x8*)&Qs[(wid * 16 + lr) * 64 + ks * 32 + lk * 8];
#pragma unroll
      for (int ni = 0; ni < 4; ni++) {
        bf16x8 bk = *(const bf16x8*)&Ks[(ni * 16 + lr) * 64 + ks * 32 + lk * 8];
        s[ni] = mfma_bf16(aq, bk, s[ni]);
      }
    }
    // online softmax over this K-tile (rows = wid*16 + lk*4 + j)
    float scl[4];
    float p[4][4];
#pragma unroll
    for (int j = 0; j < 4; j++) {
      float mx = -1e30f;
#pragma unroll
      for (int ni = 0; ni < 4; ni++) { s[ni][j] *= 0.125f; mx = fmaxf(mx, s[ni][j]); }
#pragma unroll
      for (int m = 1; m < 16; m <<= 1) mx = fmaxf(mx, __shfl_xor(mx, m));
      float mnew = fmaxf(mrow[j], mx);
      scl[j] = expf(mrow[j] - mnew);
      float rsum = 0.0f;
#pragma unroll
      for (int ni = 0; ni < 4; ni++) { p[ni][j] = expf(s[ni][j] - mnew); rsum += p[ni][j]; }
#pragma unroll
      for (int m = 1; m < 16; m <<= 1) rsum += __shfl_xor(rsum, m);
      lrow[j] = lrow[j] * scl[j] + rsum;
      mrow[j] = mnew;
    }
#pragma unroll
    for (int ni = 0; ni < 4; ni++)
#pragma unroll
      for (int j = 0; j < 4; j++) {
        accO[ni][j] *= scl[j];
        Ps[(wid * 16 + lk * 4 + j) * 64 + ni * 16 + lr] = f2b(p[ni][j]);
      }
    __syncthreads();   // P visible
    // PV: accO += P * V   (A-frag from Ps, B-frag from Vs = V^T)
#pragma unroll
    for (int ks = 0; ks < 2; ks++) {
      bf16x8 ap = *(const bf16x8*)&Ps[(wid * 16 + lr) * 64 + ks * 32 + lk * 8];
#pragma unroll
      for (int ni = 0; ni < 4; ni++) {
        bf16x8 bv = *(const bf16x8*)&Vs[(ni * 16 + lr) * 64 + ks * 32 + lk * 8];
        accO[ni] = mfma_bf16(ap, bv, accO[ni]);
      }
    }
    __syncthreads();   // all P/V/K reads done -> safe to restage
  }
  const size_t r0 = (size_t)bb * SEQ + qt * 64 + wid * 16 + lk * 4;
#pragma unroll
  for (int ni = 0; ni < 4; ni++) {
    const int col = h * 64 + ni * 16 + lr;
#pragma unroll
    for (int j = 0; j < 4; j++)
      o[(r0 + j) * D_MODEL + col] = f2b(accO[ni][j] / lrow[j]);
  }
}

// ---------------- host-side orchestration ----------------
extern "C" void kernel_launch(void* const* d_in, const int* in_sizes, int n_in,
                              void* d_out, int out_size, void* d_ws, size_t ws_size,
                              hipStream_t stream) {
  const int* tokens = (const int*)d_in[0];
  const float* emb = (const float*)d_in[1];
  const float* attn_w = (const float*)d_in[2];
  const float* attn_b = (const float*)d_in[3];
  const float* ln_a = (const float*)d_in[4];
  const float* ln_b = (const float*)d_in[5];
  const float* w1 = (const float*)d_in[6];
  const float* b1 = (const float*)d_in[7];
  const float* w2 = (const float*)d_in[8];
  const float* b2 = (const float*)d_in[9];
  const float* fc_w = (const float*)d_in[10];
  const float* fc_b = (const float*)d_in[11];

  char* ws = (char*)d_ws;
  const size_t MB = 1024 * 1024;
  float* X  = (float*)(ws);              // 16 MB fp32 residual stream [4096,1024]
  u16* WA   = (u16*)(ws + 16 * MB);      // 16 MB bf16 attn weights [L*4*D*D]
  u16* W1B  = (u16*)(ws + 32 * MB);      // 16 MB
  u16* W2B  = (u16*)(ws + 48 * MB);      // 16 MB
  char* REG = ws + 64 * MB;              // 72 MB union region
  u16* Y    = (u16*)(REG);               //  8 MB  bf16 LN out
  u16* QKV  = (u16*)(REG + 8 * MB);      // 24 MB  bf16 [4096,3072]
  u16* OB   = (u16*)(REG + 32 * MB);     //  8 MB  bf16 attn out
  u16* HB   = (u16*)(REG + 40 * MB);     // 32 MB  bf16 ffn hidden
  u16* FCW  = (u16*)(REG);               // 62.5 MB bf16 fc_w (aliases Y/QKV/OB/HB, used after)
  u16* XBF  = (u16*)(REG + 64 * MB);     //  8 MB  bf16 final x

  cvt_f32_bf16<<<1024, 256, 0, stream>>>(attn_w, WA, (NLAYER * 4 * D_MODEL * D_MODEL) / 4);
  cvt_f32_bf16<<<1024, 256, 0, stream>>>(w1, W1B, (NLAYER * FFN_DIM * D_MODEL) / 4);
  cvt_f32_bf16<<<1024, 256, 0, stream>>>(w2, W2B, (NLAYER * D_MODEL * FFN_DIM) / 4);
  embed_kernel<<<MROWS, 256, 0, stream>>>(tokens, emb, X);

  for (int l = 0; l < NLAYER; ++l) {
    ln_kernel<<<MROWS, 256, 0, stream>>>(X, ln_a + (size_t)(l * 2) * D_MODEL,
                                         ln_b + (size_t)(l * 2) * D_MODEL, Y);
    gemm_bt<0><<<dim3(3072 / 128, MROWS / 128), 256, 0, stream>>>(
        Y, WA + (size_t)l * 4 * D_MODEL * D_MODEL, attn_b + (size_t)(l * 4) * D_MODEL,
        QKV, nullptr, 3072, 1024);
    attn_kernel<<<dim3(SEQ / 64, N_HEADS, BATCH), 256, 0, stream>>>(QKV, OB);
    gemm_bt<2><<<dim3(1024 / 128, MROWS / 128), 256, 0, stream>>>(
        OB, WA + (size_t)(l * 4 + 3) * D_MODEL * D_MODEL, attn_b + (size_t)(l * 4 + 3) * D_MODEL,
        nullptr, X, 1024, 1024);
    ln_kernel<<<MROWS, 256, 0, stream>>>(X, ln_a + (size_t)(l * 2 + 1) * D_MODEL,
                                         ln_b + (size_t)(l * 2 + 1) * D_MODEL, Y);
    gemm_bt<1><<<dim3(FFN_DIM / 128, MROWS / 128), 256, 0, stream>>>(
        Y, W1B + (size_t)l * FFN_DIM * D_MODEL, b1 + (size_t)l * FFN_DIM,
        HB, nullptr, FFN_DIM, 1024);
    gemm_bt<2><<<dim3(1024 / 128, MROWS / 128), 256, 0, stream>>>(
        HB, W2B + (size_t)l * D_MODEL * FFN_DIM, b2 + (size_t)l * D_MODEL,
        nullptr, X, 1024, FFN_DIM);
  }

  cvt_f32_bf16<<<1024, 256, 0, stream>>>(X, XBF, (MROWS * D_MODEL) / 4);
  cvt_f32_bf16<<<2048, 256, 0, stream>>>(fc_w, FCW, (VOCAB * D_MODEL) / 4);
  gemm_bt<3><<<dim3(VOCAB / 128, MROWS / 128), 256, 0, stream>>>(
      XBF, FCW, fc_b, nullptr, (float*)d_out, VOCAB, 1024);
}